// Round 5
// baseline (281.124 us; speedup 1.0000x reference)
//
#include <hip/hip_runtime.h>
#include <stdint.h>

// LinearAttention MI355X round 9: barrier-free, LDS-free k_fused.
// k/v computed UNSWAPPED (lane=channel, regs=16 pixels); kv-MFMA operands
// built in-register via __shfl_xor(32) half-exchange (K-window = pixel set
// P(lhi)); each wave computes k_cg + both v halves and accumulates its own
// kv quadrants -> atomicAdd. ksum = register sum + 1 shfl. W fragments
// (packed layout from R8) loaded 16-up-front per GEMM for latency hiding.
// 8 fully independent waves/block, no __syncthreads in k_fused at all.
// B=8, DIM=256, HEADS=8, DHEAD=64, HID=512, NPIX=4096.

#define NPIX 4096
#define HIDC 512
#define DIMC 256
#define BATCH 8

typedef __attribute__((ext_vector_type(8))) short bf16x8;
typedef __attribute__((ext_vector_type(4))) float f32x4;
typedef __attribute__((ext_vector_type(16))) float f32x16;

__device__ __forceinline__ float bf2f(unsigned short h) {
    unsigned int u = ((unsigned int)h) << 16; float f;
    __builtin_memcpy(&f, &u, 4); return f;
}
__device__ __forceinline__ unsigned short f2bf(float f) {
    unsigned int u; __builtin_memcpy(&u, &f, 4);
    u += 0x7fffu + ((u >> 16) & 1u);
    return (unsigned short)(u >> 16);
}
__device__ __forceinline__ float elu1(float x) {
    return x > 0.f ? x + 1.f : __expf(x);
}
// async global->LDS, 16B per lane (used by k_y).
__device__ __forceinline__ void gl16(const unsigned short* g, unsigned short* l) {
    __builtin_amdgcn_global_load_lds(
        (__attribute__((address_space(1))) const void*)g,
        (__attribute__((address_space(3))) void*)l, 16, 0, 0);
}

// ---------------- K0a: weight conversion + fragment packing ----------------
// Wqkv (1536x256 f32) -> Wp packed bf16: row o, col c:
//   hn=o>>5, l31=o&31, ks=c>>4, lhi=(c>>3)&1, j=c&7
//   Wp[hn*8192 + ks*512 + (l31*2+lhi)*8 + j]
__global__ __launch_bounds__(256) void k_convW(
    const float* __restrict__ Wqkv, const float* __restrict__ Wout,
    unsigned short* __restrict__ Wp, unsigned short* __restrict__ Wob)
{
    int i4 = (blockIdx.x * 256 + threadIdx.x) * 4;
    const int NW1 = 1536 * 256;
    if (i4 < NW1) {
        float4 v = *(const float4*)&Wqkv[i4];
        ushort4 u; u.x = f2bf(v.x); u.y = f2bf(v.y); u.z = f2bf(v.z); u.w = f2bf(v.w);
        const int o = i4 >> 8, c = i4 & 255;
        const int hn = o >> 5, l31 = o & 31;
        const int ks = c >> 4, lhi = (c >> 3) & 1, j = c & 7;
        *(ushort4*)&Wp[hn * 8192 + ks * 512 + (l31 * 2 + lhi) * 8 + j] = u;
    } else {
        int jj = i4 - NW1;
        float4 v = *(const float4*)&Wout[jj];
        ushort4 u; u.x = f2bf(v.x); u.y = f2bf(v.y); u.z = f2bf(v.z); u.w = f2bf(v.w);
        *(ushort4*)&Wob[jj] = u;
    }
}

// ---------------- K0b: x transpose+convert ----------------
__global__ __launch_bounds__(256) void k_tx(
    const float* __restrict__ x, unsigned short* __restrict__ xT)
{
    __shared__ float tile[32][33];
    const int n0 = blockIdx.x * 32, c0 = blockIdx.y * 32, b = blockIdx.z;
    const int t = threadIdx.x;
    const int r = t >> 3, c4 = (t & 7) * 4;
    float4 v = *(const float4*)&x[((size_t)b * DIMC + c0 + r) * NPIX + n0 + c4];
    tile[r][c4 + 0] = v.x; tile[r][c4 + 1] = v.y;
    tile[r][c4 + 2] = v.z; tile[r][c4 + 3] = v.w;
    __syncthreads();
    ushort4 o;
    unsigned short* op = (unsigned short*)&o;
#pragma unroll
    for (int i = 0; i < 4; i++) op[i] = f2bf(tile[c4 + i][r]);
    *(ushort4*)&xT[((size_t)b * NPIX + n0 + r) * DIMC + c0 + c4] = o;
}

// Build the two kv-MFMA fragments from a 16-f32 accumulator (lane=channel,
// reg r = pixel rp(r,lhi) = (r&3)+8*(r>>2)+4*lhi).
// Window m=0 covers pixel set P(0) (lhi=0 lanes' pixels), slot s = reg r;
// window m=1 covers P(1). A0 = lhi ? partner_hi : own_lo;
// A1 = lhi ? own_hi : partner_lo (partner = lane^32).
#define BUILD_FRAGS(VALS, F0, F1)                                              \
    {                                                                          \
        unsigned int plo[4], phi[4];                                           \
        _Pragma("unroll")                                                      \
        for (int j = 0; j < 4; j++) {                                          \
            plo[j] = (unsigned int)f2bf(VALS[2 * j])                           \
                   | ((unsigned int)f2bf(VALS[2 * j + 1]) << 16);              \
            phi[j] = (unsigned int)f2bf(VALS[8 + 2 * j])                       \
                   | ((unsigned int)f2bf(VALS[9 + 2 * j]) << 16);              \
        }                                                                      \
        unsigned int a0[4], a1[4];                                             \
        _Pragma("unroll")                                                      \
        for (int j = 0; j < 4; j++) {                                          \
            unsigned int sh = __shfl_xor(phi[j], 32);                          \
            unsigned int sl = __shfl_xor(plo[j], 32);                          \
            a0[j] = lhi ? sh : plo[j];                                         \
            a1[j] = lhi ? phi[j] : sl;                                         \
        }                                                                      \
        __builtin_memcpy(&F0, a0, 16);                                         \
        __builtin_memcpy(&F1, a1, 16);                                         \
    }

// ---------------- K1: fused qkv GEMM + kv/ksum (no LDS, no barriers) --------
// grid (32 pixel-tiles, 8 batches), 512 threads = 8 waves (4 pix-grp x 2 ch-grp).
__global__ __launch_bounds__(512, 2) void k_fused(
    const unsigned short* __restrict__ xT,   // B x 4096 x 256
    const unsigned short* __restrict__ Wp,   // packed 1536 x 256
    const float* __restrict__ cmp,           // B x 4096
    const float* __restrict__ csp,
    unsigned short* __restrict__ qT,         // B x 4096 x 512 (pixel-major)
    float* __restrict__ kvp,                 // (B*8) x 64 x 64
    float* __restrict__ ksump)               // (B*8) x 64
{
    const int b  = blockIdx.y;
    const int m0 = blockIdx.x * 128;
    const int t  = threadIdx.x;
    const int wave = t >> 6, lane = t & 63;
    const int pg = wave >> 1, cg = wave & 1;
    const int l31 = lane & 31, lhi = lane >> 5;
    const int lidx = (l31 * 2 + lhi) * 8;    // lane's chunk in packed 1KB block

    const float cs = *csp;

    // A fragments: this wave's 32 pixel rows, all K=256.
    bf16x8 af[16];
    {
        const unsigned short* Ab = xT + ((size_t)b * NPIX + m0 + pg * 32 + l31) * DIMC;
#pragma unroll
        for (int ks = 0; ks < 16; ks++)
            af[ks] = *(const bf16x8*)&Ab[ks * 16 + lhi * 8];
    }
    // contact-map gain, one per acc reg (pixel rp(r,lhi)); loop-invariant
    const float gvl = 1.f + cs * cmp[(size_t)b * NPIX + m0 + pg * 32 + l31];
    float gvv[16];
#pragma unroll
    for (int r = 0; r < 16; r++)
        gvv[r] = __shfl(gvl, (r & 3) + 8 * (r >> 2) + 4 * lhi);

    // ---- q tiles (packed groups hn = nt*2 + cg), no barriers ----
#pragma unroll 1
    for (int nt = 0; nt < 8; nt++) {
        const unsigned short* Wr = Wp + (size_t)(nt * 2 + cg) * 8192 + lidx;
        bf16x8 wf[16];
#pragma unroll
        for (int ks = 0; ks < 16; ks++)
            wf[ks] = *(const bf16x8*)&Wr[ks * 512];
        f32x16 acc;
#pragma unroll
        for (int r = 0; r < 16; r++) acc[r] = 0.f;
#pragma unroll
        for (int ks = 0; ks < 16; ks++)
            acc = __builtin_amdgcn_mfma_f32_32x32x16_bf16(af[ks], wf[ks], acc, 0, 0, 0);
        unsigned short* qg = qT + ((size_t)b * NPIX + m0 + pg * 32) * HIDC
                           + nt * 64 + cg * 32 + l31;
#pragma unroll
        for (int r = 0; r < 16; r++) {
            const int rp = (r & 3) + 8 * (r >> 2) + 4 * lhi;
            qg[(size_t)rp * HIDC] = f2bf(elu1(acc[r]));
        }
    }

    // ---- per-head k/v + kv/ksum, fully wave-local ----
#pragma unroll 1
    for (int h = 0; h < 8; h++) {
        // k GEMM unswapped: lane = head-ch (cg*32+l31), regs = 16 pixels
        const unsigned short* Wk = Wp + (size_t)(16 + h * 2 + cg) * 8192 + lidx;
        bf16x8 wf[16];
#pragma unroll
        for (int ks = 0; ks < 16; ks++)
            wf[ks] = *(const bf16x8*)&Wk[ks * 512];
        f32x16 acc;
#pragma unroll
        for (int r = 0; r < 16; r++) acc[r] = 0.f;
#pragma unroll
        for (int ks = 0; ks < 16; ks++)
            acc = __builtin_amdgcn_mfma_f32_32x32x16_bf16(af[ks], wf[ks], acc, 0, 0, 0);

        float kf[16]; float s = 0.f;
#pragma unroll
        for (int r = 0; r < 16; r++) {
            kf[r] = elu1(acc[r]) * gvv[r];
            s += kf[r];
        }
        s += __shfl_xor(s, 32);
        if (lhi == 0)
            atomicAdd(&ksump[(size_t)(b * 8 + h) * 64 + cg * 32 + l31], s);

        bf16x8 KA0, KA1;
        BUILD_FRAGS(kf, KA0, KA1)

        float* kvb = kvp + (size_t)(b * 8 + h) * 4096;
#pragma unroll 1
        for (int e = 0; e < 2; e++) {
            // v GEMM unswapped for ch-group e (each wave does both halves)
            const unsigned short* Wv = Wp + (size_t)(32 + h * 2 + e) * 8192 + lidx;
            bf16x8 wv[16];
#pragma unroll
            for (int ks = 0; ks < 16; ks++)
                wv[ks] = *(const bf16x8*)&Wv[ks * 512];
            f32x16 vac;
#pragma unroll
            for (int r = 0; r < 16; r++) vac[r] = 0.f;
#pragma unroll
            for (int ks = 0; ks < 16; ks++)
                vac = __builtin_amdgcn_mfma_f32_32x32x16_bf16(af[ks], wv[ks], vac, 0, 0, 0);

            bf16x8 VB0, VB1;
            BUILD_FRAGS(vac, VB0, VB1)

            f32x16 kva;
#pragma unroll
            for (int r = 0; r < 16; r++) kva[r] = 0.f;
            kva = __builtin_amdgcn_mfma_f32_32x32x16_bf16(KA0, VB0, kva, 0, 0, 0);
            kva = __builtin_amdgcn_mfma_f32_32x32x16_bf16(KA1, VB1, kva, 0, 0, 0);
#pragma unroll
            for (int r = 0; r < 16; r++) {
                const int d = cg * 32 + (r & 3) + 8 * (r >> 2) + 4 * lhi;
                atomicAdd(&kvb[(size_t)d * 64 + e * 32 + l31], kva[r]);
            }
        }
    }
}

// ---------------- K3: out = z * kv^T q  (32x32x16, K=d=64) ----------------
#define LS3 72
__global__ __launch_bounds__(256) void k_out(
    const unsigned short* __restrict__ qT,   // B x 4096 x 512
    const float* __restrict__ kv, const float* __restrict__ ksum,
    unsigned short* __restrict__ outT)       // B x 4096 x 512
{
    const int bh = blockIdx.y, p0 = blockIdx.x * 128;
    const int b = bh >> 3, h = bh & 7;
    const int t = threadIdx.x, wave = t >> 6, lane = t & 63;
    const int l31 = lane & 31, lhi = lane >> 5;

    __shared__ unsigned short Aq[128 * LS3];  // [pixel][d]
    __shared__ unsigned short Bv[96 * LS3];   // [n][d]: 0..63 kvT, 64 hi, 65 lo, 66..95 zero

    const unsigned short* qg = qT + ((size_t)b * NPIX + p0) * HIDC + h * 64;
#pragma unroll
    for (int i = 0; i < 4; i++) {
        int idx = t + i * 256;
        int row = idx >> 3, c8 = (idx & 7) * 8;
        *(uint4*)&Aq[row * LS3 + c8] = *(const uint4*)&qg[(size_t)row * HIDC + c8];
    }
    const float* kvg = kv + (size_t)bh * 4096;
#pragma unroll
    for (int i = 0; i < 16; i++) {
        int idx = t + i * 256;
        int d = idx >> 6, e = idx & 63;
        Bv[e * LS3 + d] = f2bf(kvg[idx]);
    }
    if (t < 64) {
        float ksv = ksum[bh * 64 + t];
        unsigned short hi = f2bf(ksv);
        Bv[64 * LS3 + t] = hi;
        Bv[65 * LS3 + t] = f2bf(ksv - bf2f(hi));
    }
    for (int i = t; i < 30 * 64; i += 256)
        Bv[(66 + (i >> 6)) * LS3 + (i & 63)] = 0;
    __syncthreads();

    f32x16 acc[3];
#pragma unroll
    for (int j = 0; j < 3; j++)
#pragma unroll
        for (int r = 0; r < 16; r++) acc[j][r] = 0.f;

#pragma unroll
    for (int ksub = 0; ksub < 4; ksub++) {
        const int koff = ksub * 16 + lhi * 8;
        bf16x8 af = *(const bf16x8*)&Aq[(wave * 32 + l31) * LS3 + koff];
#pragma unroll
        for (int nf = 0; nf < 3; nf++) {
            bf16x8 bfg = *(const bf16x8*)&Bv[(nf * 32 + l31) * LS3 + koff];
            acc[nf] = __builtin_amdgcn_mfma_f32_32x32x16_bf16(af, bfg, acc[nf], 0, 0, 0);
        }
    }

    unsigned short* og = outT + ((size_t)b * NPIX + p0 + wave * 32) * HIDC + h * 64;
#pragma unroll
    for (int r = 0; r < 16; r++) {
        float hi = __shfl(acc[2][r], lane & 32);
        float lo = __shfl(acc[2][r], (lane & 32) | 1);
        float z = 1.f / (hi + lo + 1e-6f);
        int prow = (r & 3) + 8 * (r >> 2) + 4 * lhi;
#pragma unroll
        for (int nf = 0; nf < 2; nf++)
            og[(size_t)prow * HIDC + nf * 32 + l31] = f2bf(acc[nf][r] * z);
    }
}

// ---------------- K4: y = outT @ Wob^T + bout (16x16x32, async staging) ------
__global__ __launch_bounds__(256) void k_y(
    const unsigned short* __restrict__ outT,  // B x 4096 x 512
    const unsigned short* __restrict__ Wob,   // 256 x 512
    const float* __restrict__ bout,
    float* __restrict__ y)                    // B x 256 x 4096
{
    const int b  = blockIdx.z;
    const int m0 = blockIdx.x * 128;
    const int n0 = blockIdx.y * 128;
    const int t = threadIdx.x;
    const int wave = t >> 6, lane = t & 63;
    const int wm = wave >> 1, wn = wave & 1;
    const int lrow = lane & 15, quad = lane >> 4;

    __shared__ unsigned short As[128 * 64];
    __shared__ unsigned short Bs[128 * 64];

    const unsigned short* Ag = outT + ((size_t)b * NPIX + m0) * HIDC;
    const unsigned short* Bg = Wob + (size_t)n0 * HIDC;

    f32x4 acc[4][4];
#pragma unroll
    for (int i = 0; i < 4; i++)
#pragma unroll
        for (int j = 0; j < 4; j++) acc[i][j] = (f32x4){0.f, 0.f, 0.f, 0.f};

    const int r8  = lane >> 3;
    const int jg8 = (((lane & 7) ^ r8) & 7) * 8;
    const int xswA = (lrow & 7);

    for (int k0 = 0; k0 < HIDC; k0 += 64) {
#pragma unroll
        for (int i = 0; i < 4; i++) {
            const int rowg = wave * 32 + i * 8;
            gl16(&Ag[(size_t)(rowg + r8) * HIDC + k0 + jg8], &As[rowg * 64]);
            gl16(&Bg[(size_t)(rowg + r8) * HIDC + k0 + jg8], &Bs[rowg * 64]);
        }
        __syncthreads();
#pragma unroll
        for (int ksb = 0; ksb < 2; ksb++) {
            bf16x8 af[4], bfr[4];
#pragma unroll
            for (int mt = 0; mt < 4; mt++) {
                const int row = wm * 64 + mt * 16 + lrow;
                af[mt] = *(const bf16x8*)&As[row * 64 + (((ksb * 4 + quad) ^ xswA)) * 8];
            }
#pragma unroll
            for (int nt = 0; nt < 4; nt++) {
                const int row = wn * 64 + nt * 16 + lrow;
                bfr[nt] = *(const bf16x8*)&Bs[row * 64 + (((ksb * 4 + quad) ^ xswA)) * 8];
            }
#pragma unroll
            for (int mt = 0; mt < 4; mt++)
#pragma unroll
                for (int nt = 0; nt < 4; nt++)
                    acc[mt][nt] = __builtin_amdgcn_mfma_f32_16x16x32_bf16(
                        af[mt], bfr[nt], acc[mt][nt], 0, 0, 0);
        }
        __syncthreads();
    }

#pragma unroll
    for (int mt = 0; mt < 4; mt++) {
        const int pixel0 = m0 + wm * 64 + mt * 16 + quad * 4;
#pragma unroll
        for (int nt = 0; nt < 4; nt++) {
            const int o = n0 + wn * 64 + nt * 16 + lrow;
            const float bias = bout[o];
            f32x4 a = acc[mt][nt];
            float4 st; st.x = a[0] + bias; st.y = a[1] + bias;
            st.z = a[2] + bias; st.w = a[3] + bias;
            *(float4*)&y[((size_t)b * DIMC + o) * NPIX + pixel0] = st;
        }
    }
}

extern "C" void kernel_launch(void* const* d_in, const int* in_sizes, int n_in,
                              void* d_out, int out_size, void* d_ws, size_t ws_size,
                              hipStream_t stream) {
    (void)in_sizes; (void)n_in; (void)out_size; (void)ws_size;
    const float* x    = (const float*)d_in[0];
    const float* cm   = (const float*)d_in[1];
    const float* Wqkv = (const float*)d_in[2];
    const float* Wout = (const float*)d_in[3];
    const float* bout = (const float*)d_in[4];
    const float* csp  = (const float*)d_in[5];
    float* y = (float*)d_out;

    const size_t qn = (size_t)BATCH * HIDC * NPIX;
    char* ws = (char*)d_ws;
    unsigned short* qT   = (unsigned short*)ws;                 ws += qn * 2;
    unsigned short* outT = (unsigned short*)ws;                 ws += qn * 2;
    unsigned short* xT   = outT;  // alias OK: k_tx->k_fused reads xT before k_out writes outT
    float* kvp   = (float*)ws;                                  ws += (size_t)64 * 64 * 64 * 4;
    float* ksump = (float*)ws;                                  ws += (size_t)64 * 64 * 4;
    unsigned short* Wp  = (unsigned short*)ws;                  ws += (size_t)1536 * 256 * 2;
    unsigned short* Wob = (unsigned short*)ws;

    hipMemsetAsync(kvp, 0, ((size_t)64 * 64 * 64 + 64 * 64) * sizeof(float), stream);
    k_convW<<<512, 256, 0, stream>>>(Wqkv, Wout, Wp, Wob);
    k_tx   <<<dim3(128, 8, 8), 256, 0, stream>>>(x, xT);
    k_fused<<<dim3(32, 8),     512, 0, stream>>>(xT, Wp, cm, csp, qT, kvp, ksump);
    k_out  <<<dim3(32, 64),    256, 0, stream>>>(qT, kvp, ksump, outT);
    k_y    <<<dim3(32, 2, 8),  256, 0, stream>>>(outT, Wob, bout, y);
}

// Round 6
// 218.186 us; speedup vs baseline: 1.2885x; 1.2885x over previous
//
#include <hip/hip_runtime.h>
#include <stdint.h>

// LinearAttention MI355X round 10: back to the proven 3072-block GEMM geometry
// (round-0 k_qkv core, 57us measured) with kv/ksum fused as a per-block
// epilogue. Grid (32,12,8): y<4 = q-blocks (verbatim round-0 sect-0 path);
// y>=4 = head-blocks (composite k|v B-tile, register ksum, LDS bounce reusing
// the 32KB staging buffer, R5-verified kv-MFMA + atomics). k/v never hit HBM.
// B=8, DIM=256, HEADS=8, DHEAD=64, HID=512, NPIX=4096.

#define NPIX 4096
#define HIDC 512
#define DIMC 256
#define BATCH 8

typedef __attribute__((ext_vector_type(8))) short bf16x8;
typedef __attribute__((ext_vector_type(4))) float f32x4;
typedef __attribute__((ext_vector_type(16))) float f32x16;

__device__ __forceinline__ float bf2f(unsigned short h) {
    unsigned int u = ((unsigned int)h) << 16; float f;
    __builtin_memcpy(&f, &u, 4); return f;
}
__device__ __forceinline__ unsigned short f2bf(float f) {
    unsigned int u; __builtin_memcpy(&u, &f, 4);
    u += 0x7fffu + ((u >> 16) & 1u);
    return (unsigned short)(u >> 16);
}
__device__ __forceinline__ float elu1(float x) {
    return x > 0.f ? x + 1.f : __expf(x);
}
// async global->LDS, 16B per lane. LDS dest = wave-uniform base + lane*16.
__device__ __forceinline__ void gl16(const unsigned short* g, unsigned short* l) {
    __builtin_amdgcn_global_load_lds(
        (__attribute__((address_space(1))) const void*)g,
        (__attribute__((address_space(3))) void*)l, 16, 0, 0);
}

// ---------------- K0a: weight conversion (linear bf16) ----------------
__global__ __launch_bounds__(256) void k_convW(
    const float* __restrict__ Wqkv, const float* __restrict__ Wout,
    unsigned short* __restrict__ Wb, unsigned short* __restrict__ Wob)
{
    int i4 = (blockIdx.x * 256 + threadIdx.x) * 4;
    const int NW1 = 1536 * 256;
    float4 v; unsigned short* dst;
    if (i4 < NW1) { v = *(const float4*)&Wqkv[i4]; dst = Wb + i4; }
    else { int j = i4 - NW1; v = *(const float4*)&Wout[j]; dst = Wob + j; }
    ushort4 o; o.x = f2bf(v.x); o.y = f2bf(v.y); o.z = f2bf(v.z); o.w = f2bf(v.w);
    *(ushort4*)dst = o;
}

// ---------------- K0b: x transpose+convert ----------------
__global__ __launch_bounds__(256) void k_tx(
    const float* __restrict__ x, unsigned short* __restrict__ xT)
{
    __shared__ float tile[32][33];
    const int n0 = blockIdx.x * 32, c0 = blockIdx.y * 32, b = blockIdx.z;
    const int t = threadIdx.x;
    const int r = t >> 3, c4 = (t & 7) * 4;
    float4 v = *(const float4*)&x[((size_t)b * DIMC + c0 + r) * NPIX + n0 + c4];
    tile[r][c4 + 0] = v.x; tile[r][c4 + 1] = v.y;
    tile[r][c4 + 2] = v.z; tile[r][c4 + 3] = v.w;
    __syncthreads();
    ushort4 o;
    unsigned short* op = (unsigned short*)&o;
#pragma unroll
    for (int i = 0; i < 4; i++) op[i] = f2bf(tile[c4 + i][r]);
    *(ushort4*)&xT[((size_t)b * NPIX + n0 + r) * DIMC + c0 + c4] = o;
}

// ---------------- K1: fused qkv GEMM + kv/ksum epilogue ----------------
// grid (32 px-tiles, 12, 8 b) = 3072 blocks, 256 threads (4 waves, 2x2 of
// 64x64 within a 128x128 output tile). Round-0 staging: LDS 16B chunk c of
// row r holds global chunk c ^ (r&7).
// Head-block bounce: kvS[128 rows][128 px], rows 0..63 = k (elu*gain),
// 64..127 = v; ushort idx row*128 + (px ^ ((row&7)<<3)).
__global__ __launch_bounds__(256) void k_fused(
    const unsigned short* __restrict__ xT,   // B x 4096 x 256
    const unsigned short* __restrict__ Wb,   // 1536 x 256
    const float* __restrict__ cmp,           // B x 4096
    const float* __restrict__ csp,
    unsigned short* __restrict__ qT,         // B x 4096 x 512 (pixel-major)
    float* __restrict__ kvp,                 // (B*8) x 64 x 64
    float* __restrict__ ksump)               // (B*8) x 64
{
    const int b  = blockIdx.z;
    const int m0 = blockIdx.x * 128;
    const int yb = blockIdx.y;               // 0..3 = q, 4..11 = head yb-4
    const int h  = yb - 4;
    const int t = threadIdx.x;
    const int wave = t >> 6, lane = t & 63;
    const int wm = wave >> 1, wn = wave & 1;
    const int l31 = lane & 31, lhi = lane >> 5;

    __shared__ unsigned short sh[128 * 128];        // 32 KB
    unsigned short* As  = sh;                       // [128 px][64 k]
    unsigned short* Bs  = sh + 128 * 64;            // [128 o ][64 k]
    unsigned short* kvS = sh;                       // epilogue reuse [128][128]

    const unsigned short* Ag = xT + ((size_t)b * NPIX + m0) * DIMC;

    f32x16 acc[2][2];
#pragma unroll
    for (int i = 0; i < 2; i++)
#pragma unroll
        for (int j = 0; j < 2; j++)
#pragma unroll
            for (int r = 0; r < 16; r++) acc[i][j][r] = 0.f;

    const int r8  = lane >> 3;
    const int jg8 = (((lane & 7) ^ r8) & 7) * 8;     // swizzled global chunk
    const int xsw = (l31 & 7);

    for (int k0 = 0; k0 < DIMC; k0 += 64) {
#pragma unroll
        for (int i = 0; i < 4; i++) {
            const int rowg = wave * 32 + i * 8;
            const int arow = rowg + r8;
            gl16(&Ag[(size_t)arow * DIMC + k0 + jg8], &As[rowg * 64]);
            int wrow;
            if (yb < 4) wrow = yb * 128 + arow;
            else wrow = (arow < 64) ? (512 + h * 64 + arow)
                                    : (1024 + h * 64 + (arow - 64));
            gl16(&Wb[(size_t)wrow * DIMC + k0 + jg8], &Bs[rowg * 64]);
        }
        __syncthreads();
#pragma unroll
        for (int ks = 0; ks < 4; ks++) {
            const int coff = ((ks * 2 + lhi) ^ xsw) * 8;
            bf16x8 af[2], bfg[2];
#pragma unroll
            for (int fm = 0; fm < 2; fm++)
                af[fm] = *(const bf16x8*)&As[(wm * 64 + fm * 32 + l31) * 64 + coff];
#pragma unroll
            for (int fn = 0; fn < 2; fn++)
                bfg[fn] = *(const bf16x8*)&Bs[(wn * 64 + fn * 32 + l31) * 64 + coff];
#pragma unroll
            for (int fm = 0; fm < 2; fm++)
#pragma unroll
                for (int fn = 0; fn < 2; fn++)
                    acc[fm][fn] = __builtin_amdgcn_mfma_f32_32x32x16_bf16(
                        af[fm], bfg[fn], acc[fm][fn], 0, 0, 0);
        }
        __syncthreads();
    }

    if (yb < 4) {
        // ---- q epilogue (verbatim round-0 sect-0) ----
        const int n0 = yb * 128;
#pragma unroll
        for (int fm = 0; fm < 2; fm++) {
            const int pbase = m0 + wm * 64 + fm * 32;
#pragma unroll
            for (int fn = 0; fn < 2; fn++) {
                const int o = n0 + wn * 64 + fn * 32 + l31;
#pragma unroll
                for (int r = 0; r < 16; r++) {
                    int prow = pbase + (r & 3) + 8 * (r >> 2) + 4 * lhi;
                    qT[((size_t)b * NPIX + prow) * HIDC + o] = f2bf(elu1(acc[fm][fn][r]));
                }
            }
        }
        return;
    }

    // ---- head epilogue: ksum (registers) + bounce + kv-MFMA + atomics ----
    const float cs = *csp;
    float gv4[2];
#pragma unroll
    for (int fm = 0; fm < 2; fm++)
        gv4[fm] = 1.f + cs * cmp[(size_t)b * NPIX + m0 + wm * 64 + fm * 32 + l31];

    float ks0 = 0.f, ks1 = 0.f;
#pragma unroll
    for (int fm = 0; fm < 2; fm++) {
#pragma unroll
        for (int r = 0; r < 16; r++) {
            const int rp = (r & 3) + 8 * (r >> 2) + 4 * lhi;
            const float g = __shfl(gv4[fm], rp);     // lane rp holds pixel base+rp
            const int px = wm * 64 + fm * 32 + rp;
#pragma unroll
            for (int fn = 0; fn < 2; fn++) {
                const int o = wn * 64 + fn * 32 + l31;   // <64: k-ch, >=64: v-ch
                float val = acc[fm][fn][r];
                unsigned short st;
                if (o < 64) {
                    float kvl = elu1(val) * g;
                    if (fn == 0) ks0 += kvl; else ks1 += kvl;
                    st = f2bf(kvl);
                } else {
                    st = f2bf(val);
                }
                kvS[(size_t)o * 128 + (px ^ ((o & 7) << 3))] = st;
            }
        }
    }
    if (wn == 0) {
        atomicAdd(&ksump[(size_t)(b * 8 + h) * 64 + l31], ks0);
        atomicAdd(&ksump[(size_t)(b * 8 + h) * 64 + 32 + l31], ks1);
    }
    __syncthreads();   // kvS fully written

    // kv partial: 64x64 over K=128 pixels; 4 waves, 32x32 quadrants
    f32x16 kva;
#pragma unroll
    for (int r = 0; r < 16; r++) kva[r] = 0.f;
#pragma unroll
    for (int pk = 0; pk < 8; pk++) {
        const int co = ((pk * 2 + lhi) ^ (l31 & 7)) * 8;
        bf16x8 kf = *(const bf16x8*)&kvS[(size_t)(wm * 32 + l31) * 128 + co];
        bf16x8 vf = *(const bf16x8*)&kvS[(size_t)(64 + wn * 32 + l31) * 128 + co];
        kva = __builtin_amdgcn_mfma_f32_32x32x16_bf16(kf, vf, kva, 0, 0, 0);
    }
    float* kvb = kvp + (size_t)(b * 8 + h) * 4096;
#pragma unroll
    for (int r = 0; r < 16; r++) {
        const int d = wm * 32 + (r & 3) + 8 * (r >> 2) + 4 * lhi;
        atomicAdd(&kvb[(size_t)d * 64 + wn * 32 + l31], kva[r]);
    }
}

// ---------------- K3: out = z * kv^T q  (32x32x16, K=d=64) ----------------
#define LS3 72
__global__ __launch_bounds__(256) void k_out(
    const unsigned short* __restrict__ qT,   // B x 4096 x 512
    const float* __restrict__ kv, const float* __restrict__ ksum,
    unsigned short* __restrict__ outT)       // B x 4096 x 512
{
    const int bh = blockIdx.y, p0 = blockIdx.x * 128;
    const int b = bh >> 3, h = bh & 7;
    const int t = threadIdx.x, wave = t >> 6, lane = t & 63;
    const int l31 = lane & 31, lhi = lane >> 5;

    __shared__ unsigned short Aq[128 * LS3];  // [pixel][d]
    __shared__ unsigned short Bv[96 * LS3];   // [n][d]: 0..63 kvT, 64 hi, 65 lo, 66..95 zero

    const unsigned short* qg = qT + ((size_t)b * NPIX + p0) * HIDC + h * 64;
#pragma unroll
    for (int i = 0; i < 4; i++) {
        int idx = t + i * 256;
        int row = idx >> 3, c8 = (idx & 7) * 8;
        *(uint4*)&Aq[row * LS3 + c8] = *(const uint4*)&qg[(size_t)row * HIDC + c8];
    }
    const float* kvg = kv + (size_t)bh * 4096;
#pragma unroll
    for (int i = 0; i < 16; i++) {
        int idx = t + i * 256;
        int d = idx >> 6, e = idx & 63;
        Bv[e * LS3 + d] = f2bf(kvg[idx]);
    }
    if (t < 64) {
        float ksv = ksum[bh * 64 + t];
        unsigned short hi = f2bf(ksv);
        Bv[64 * LS3 + t] = hi;
        Bv[65 * LS3 + t] = f2bf(ksv - bf2f(hi));
    }
    for (int i = t; i < 30 * 64; i += 256)
        Bv[(66 + (i >> 6)) * LS3 + (i & 63)] = 0;
    __syncthreads();

    f32x16 acc[3];
#pragma unroll
    for (int j = 0; j < 3; j++)
#pragma unroll
        for (int r = 0; r < 16; r++) acc[j][r] = 0.f;

#pragma unroll
    for (int ksub = 0; ksub < 4; ksub++) {
        const int koff = ksub * 16 + lhi * 8;
        bf16x8 af = *(const bf16x8*)&Aq[(wave * 32 + l31) * LS3 + koff];
#pragma unroll
        for (int nf = 0; nf < 3; nf++) {
            bf16x8 bfg = *(const bf16x8*)&Bv[(nf * 32 + l31) * LS3 + koff];
            acc[nf] = __builtin_amdgcn_mfma_f32_32x32x16_bf16(af, bfg, acc[nf], 0, 0, 0);
        }
    }

    unsigned short* og = outT + ((size_t)b * NPIX + p0 + wave * 32) * HIDC + h * 64;
#pragma unroll
    for (int r = 0; r < 16; r++) {
        float hi = __shfl(acc[2][r], lane & 32);
        float lo = __shfl(acc[2][r], (lane & 32) | 1);
        float z = 1.f / (hi + lo + 1e-6f);
        int prow = (r & 3) + 8 * (r >> 2) + 4 * lhi;
#pragma unroll
        for (int nf = 0; nf < 2; nf++)
            og[(size_t)prow * HIDC + nf * 32 + l31] = f2bf(acc[nf][r] * z);
    }
}

// ---------------- K4: y = outT @ Wob^T + bout (16x16x32, async staging) ------
__global__ __launch_bounds__(256) void k_y(
    const unsigned short* __restrict__ outT,  // B x 4096 x 512
    const unsigned short* __restrict__ Wob,   // 256 x 512
    const float* __restrict__ bout,
    float* __restrict__ y)                    // B x 256 x 4096
{
    const int b  = blockIdx.z;
    const int m0 = blockIdx.x * 128;
    const int n0 = blockIdx.y * 128;
    const int t = threadIdx.x;
    const int wave = t >> 6, lane = t & 63;
    const int wm = wave >> 1, wn = wave & 1;
    const int lrow = lane & 15, quad = lane >> 4;

    __shared__ unsigned short As[128 * 64];
    __shared__ unsigned short Bs[128 * 64];

    const unsigned short* Ag = outT + ((size_t)b * NPIX + m0) * HIDC;
    const unsigned short* Bg = Wob + (size_t)n0 * HIDC;

    f32x4 acc[4][4];
#pragma unroll
    for (int i = 0; i < 4; i++)
#pragma unroll
        for (int j = 0; j < 4; j++) acc[i][j] = (f32x4){0.f, 0.f, 0.f, 0.f};

    const int r8  = lane >> 3;
    const int jg8 = (((lane & 7) ^ r8) & 7) * 8;
    const int xswA = (lrow & 7);

    for (int k0 = 0; k0 < HIDC; k0 += 64) {
#pragma unroll
        for (int i = 0; i < 4; i++) {
            const int rowg = wave * 32 + i * 8;
            gl16(&Ag[(size_t)(rowg + r8) * HIDC + k0 + jg8], &As[rowg * 64]);
            gl16(&Bg[(size_t)(rowg + r8) * HIDC + k0 + jg8], &Bs[rowg * 64]);
        }
        __syncthreads();
#pragma unroll
        for (int ksb = 0; ksb < 2; ksb++) {
            bf16x8 af[4], bfr[4];
#pragma unroll
            for (int mt = 0; mt < 4; mt++) {
                const int row = wm * 64 + mt * 16 + lrow;
                af[mt] = *(const bf16x8*)&As[row * 64 + (((ksb * 4 + quad) ^ xswA)) * 8];
            }
#pragma unroll
            for (int nt = 0; nt < 4; nt++) {
                const int row = wn * 64 + nt * 16 + lrow;
                bfr[nt] = *(const bf16x8*)&Bs[row * 64 + (((ksb * 4 + quad) ^ xswA)) * 8];
            }
#pragma unroll
            for (int mt = 0; mt < 4; mt++)
#pragma unroll
                for (int nt = 0; nt < 4; nt++)
                    acc[mt][nt] = __builtin_amdgcn_mfma_f32_16x16x32_bf16(
                        af[mt], bfr[nt], acc[mt][nt], 0, 0, 0);
        }
        __syncthreads();
    }

#pragma unroll
    for (int mt = 0; mt < 4; mt++) {
        const int pixel0 = m0 + wm * 64 + mt * 16 + quad * 4;
#pragma unroll
        for (int nt = 0; nt < 4; nt++) {
            const int o = n0 + wn * 64 + nt * 16 + lrow;
            const float bias = bout[o];
            f32x4 a = acc[mt][nt];
            float4 st; st.x = a[0] + bias; st.y = a[1] + bias;
            st.z = a[2] + bias; st.w = a[3] + bias;
            *(float4*)&y[((size_t)b * DIMC + o) * NPIX + pixel0] = st;
        }
    }
}

extern "C" void kernel_launch(void* const* d_in, const int* in_sizes, int n_in,
                              void* d_out, int out_size, void* d_ws, size_t ws_size,
                              hipStream_t stream) {
    (void)in_sizes; (void)n_in; (void)out_size; (void)ws_size;
    const float* x    = (const float*)d_in[0];
    const float* cm   = (const float*)d_in[1];
    const float* Wqkv = (const float*)d_in[2];
    const float* Wout = (const float*)d_in[3];
    const float* bout = (const float*)d_in[4];
    const float* csp  = (const float*)d_in[5];
    float* y = (float*)d_out;

    const size_t qn = (size_t)BATCH * HIDC * NPIX;
    char* ws = (char*)d_ws;
    unsigned short* qT   = (unsigned short*)ws;                 ws += qn * 2;
    unsigned short* outT = (unsigned short*)ws;                 ws += qn * 2;
    unsigned short* xT   = outT;  // alias OK: k_tx->k_fused reads xT before k_out writes outT
    float* kvp   = (float*)ws;                                  ws += (size_t)64 * 64 * 64 * 4;
    float* ksump = (float*)ws;                                  ws += (size_t)64 * 64 * 4;
    unsigned short* Wb  = (unsigned short*)ws;                  ws += (size_t)1536 * 256 * 2;
    unsigned short* Wob = (unsigned short*)ws;

    hipMemsetAsync(kvp, 0, ((size_t)64 * 64 * 64 + 64 * 64) * sizeof(float), stream);
    k_convW<<<512, 256, 0, stream>>>(Wqkv, Wout, Wb, Wob);
    k_tx   <<<dim3(128, 8, 8), 256, 0, stream>>>(x, xT);
    k_fused<<<dim3(32, 12, 8), 256, 0, stream>>>(xT, Wb, cm, csp, qT, kvp, ksump);
    k_out  <<<dim3(32, 64),    256, 0, stream>>>(qT, kvp, ksump, outT);
    k_y    <<<dim3(32, 2, 8),  256, 0, stream>>>(outT, Wob, bout, y);
}

// Round 7
// 210.126 us; speedup vs baseline: 1.3379x; 1.0384x over previous
//
#include <hip/hip_runtime.h>
#include <stdint.h>

// LinearAttention MI355X round 11: round-10 structure, atomic-free kv path.
// Head-blocks write private 64x64 f32 kv partials (coalesced stores) to
// kvq[(bh*32)+slot]; new k_kvred sums 32 slots -> kvp. kv atomics 8.4M -> 0
// (ksum atomics 0.5M kept). LDS bounce packed to ds_write_b64 (16/thread,
// was 64 scalar u16). Everything else verbatim round-10.
// B=8, DIM=256, HEADS=8, DHEAD=64, HID=512, NPIX=4096.

#define NPIX 4096
#define HIDC 512
#define DIMC 256
#define BATCH 8

typedef __attribute__((ext_vector_type(8))) short bf16x8;
typedef __attribute__((ext_vector_type(4))) float f32x4;
typedef __attribute__((ext_vector_type(16))) float f32x16;

__device__ __forceinline__ float bf2f(unsigned short h) {
    unsigned int u = ((unsigned int)h) << 16; float f;
    __builtin_memcpy(&f, &u, 4); return f;
}
__device__ __forceinline__ unsigned short f2bf(float f) {
    unsigned int u; __builtin_memcpy(&u, &f, 4);
    u += 0x7fffu + ((u >> 16) & 1u);
    return (unsigned short)(u >> 16);
}
__device__ __forceinline__ float elu1(float x) {
    return x > 0.f ? x + 1.f : __expf(x);
}
// async global->LDS, 16B per lane. LDS dest = wave-uniform base + lane*16.
__device__ __forceinline__ void gl16(const unsigned short* g, unsigned short* l) {
    __builtin_amdgcn_global_load_lds(
        (__attribute__((address_space(1))) const void*)g,
        (__attribute__((address_space(3))) void*)l, 16, 0, 0);
}

// ---------------- K0a: weight conversion (linear bf16) ----------------
__global__ __launch_bounds__(256) void k_convW(
    const float* __restrict__ Wqkv, const float* __restrict__ Wout,
    unsigned short* __restrict__ Wb, unsigned short* __restrict__ Wob)
{
    int i4 = (blockIdx.x * 256 + threadIdx.x) * 4;
    const int NW1 = 1536 * 256;
    float4 v; unsigned short* dst;
    if (i4 < NW1) { v = *(const float4*)&Wqkv[i4]; dst = Wb + i4; }
    else { int j = i4 - NW1; v = *(const float4*)&Wout[j]; dst = Wob + j; }
    ushort4 o; o.x = f2bf(v.x); o.y = f2bf(v.y); o.z = f2bf(v.z); o.w = f2bf(v.w);
    *(ushort4*)dst = o;
}

// ---------------- K0b: x transpose+convert ----------------
__global__ __launch_bounds__(256) void k_tx(
    const float* __restrict__ x, unsigned short* __restrict__ xT)
{
    __shared__ float tile[32][33];
    const int n0 = blockIdx.x * 32, c0 = blockIdx.y * 32, b = blockIdx.z;
    const int t = threadIdx.x;
    const int r = t >> 3, c4 = (t & 7) * 4;
    float4 v = *(const float4*)&x[((size_t)b * DIMC + c0 + r) * NPIX + n0 + c4];
    tile[r][c4 + 0] = v.x; tile[r][c4 + 1] = v.y;
    tile[r][c4 + 2] = v.z; tile[r][c4 + 3] = v.w;
    __syncthreads();
    ushort4 o;
    unsigned short* op = (unsigned short*)&o;
#pragma unroll
    for (int i = 0; i < 4; i++) op[i] = f2bf(tile[c4 + i][r]);
    *(ushort4*)&xT[((size_t)b * NPIX + n0 + r) * DIMC + c0 + c4] = o;
}

// ---------------- K1: fused qkv GEMM + kv/ksum epilogue ----------------
// grid (32 px-tiles, 12, 8 b) = 3072 blocks, 256 threads (4 waves, 2x2 of
// 64x64 within a 128x128 output tile). Round-0 staging: LDS 16B chunk c of
// row r holds global chunk c ^ (r&7).
// Head-block bounce: kvS[128 rows][128 px], rows 0..63 = k (elu*gain),
// 64..127 = v; ushort idx row*128 + (px ^ ((row&7)<<3)).
__global__ __launch_bounds__(256) void k_fused(
    const unsigned short* __restrict__ xT,   // B x 4096 x 256
    const unsigned short* __restrict__ Wb,   // 1536 x 256
    const float* __restrict__ cmp,           // B x 4096
    const float* __restrict__ csp,
    unsigned short* __restrict__ qT,         // B x 4096 x 512 (pixel-major)
    float* __restrict__ kvq,                 // (B*8) x 32 x 64 x 64 partials
    float* __restrict__ ksump)               // (B*8) x 64
{
    const int b  = blockIdx.z;
    const int m0 = blockIdx.x * 128;
    const int yb = blockIdx.y;               // 0..3 = q, 4..11 = head yb-4
    const int h  = yb - 4;
    const int t = threadIdx.x;
    const int wave = t >> 6, lane = t & 63;
    const int wm = wave >> 1, wn = wave & 1;
    const int l31 = lane & 31, lhi = lane >> 5;

    __shared__ unsigned short sh[128 * 128];        // 32 KB
    unsigned short* As  = sh;                       // [128 px][64 k]
    unsigned short* Bs  = sh + 128 * 64;            // [128 o ][64 k]
    unsigned short* kvS = sh;                       // epilogue reuse [128][128]

    const unsigned short* Ag = xT + ((size_t)b * NPIX + m0) * DIMC;

    f32x16 acc[2][2];
#pragma unroll
    for (int i = 0; i < 2; i++)
#pragma unroll
        for (int j = 0; j < 2; j++)
#pragma unroll
            for (int r = 0; r < 16; r++) acc[i][j][r] = 0.f;

    const int r8  = lane >> 3;
    const int jg8 = (((lane & 7) ^ r8) & 7) * 8;     // swizzled global chunk
    const int xsw = (l31 & 7);

    for (int k0 = 0; k0 < DIMC; k0 += 64) {
#pragma unroll
        for (int i = 0; i < 4; i++) {
            const int rowg = wave * 32 + i * 8;
            const int arow = rowg + r8;
            gl16(&Ag[(size_t)arow * DIMC + k0 + jg8], &As[rowg * 64]);
            int wrow;
            if (yb < 4) wrow = yb * 128 + arow;
            else wrow = (arow < 64) ? (512 + h * 64 + arow)
                                    : (1024 + h * 64 + (arow - 64));
            gl16(&Wb[(size_t)wrow * DIMC + k0 + jg8], &Bs[rowg * 64]);
        }
        __syncthreads();
#pragma unroll
        for (int ks = 0; ks < 4; ks++) {
            const int coff = ((ks * 2 + lhi) ^ xsw) * 8;
            bf16x8 af[2], bfg[2];
#pragma unroll
            for (int fm = 0; fm < 2; fm++)
                af[fm] = *(const bf16x8*)&As[(wm * 64 + fm * 32 + l31) * 64 + coff];
#pragma unroll
            for (int fn = 0; fn < 2; fn++)
                bfg[fn] = *(const bf16x8*)&Bs[(wn * 64 + fn * 32 + l31) * 64 + coff];
#pragma unroll
            for (int fm = 0; fm < 2; fm++)
#pragma unroll
                for (int fn = 0; fn < 2; fn++)
                    acc[fm][fn] = __builtin_amdgcn_mfma_f32_32x32x16_bf16(
                        af[fm], bfg[fn], acc[fm][fn], 0, 0, 0);
        }
        __syncthreads();
    }

    if (yb < 4) {
        // ---- q epilogue (verbatim round-0 sect-0) ----
        const int n0 = yb * 128;
#pragma unroll
        for (int fm = 0; fm < 2; fm++) {
            const int pbase = m0 + wm * 64 + fm * 32;
#pragma unroll
            for (int fn = 0; fn < 2; fn++) {
                const int o = n0 + wn * 64 + fn * 32 + l31;
#pragma unroll
                for (int r = 0; r < 16; r++) {
                    int prow = pbase + (r & 3) + 8 * (r >> 2) + 4 * lhi;
                    qT[((size_t)b * NPIX + prow) * HIDC + o] = f2bf(elu1(acc[fm][fn][r]));
                }
            }
        }
        return;
    }

    // ---- head epilogue: ksum (registers) + packed bounce + kv-MFMA + stores --
    const float cs = *csp;
    const bool isK = (wn == 0);
    float gv4[2];
#pragma unroll
    for (int fm = 0; fm < 2; fm++)
        gv4[fm] = 1.f + cs * cmp[(size_t)b * NPIX + m0 + wm * 64 + fm * 32 + l31];

    // gain per (fm, r): gain of pixel base + rp(r,lhi); uniform across l31
    float gk[2][16];
#pragma unroll
    for (int fm = 0; fm < 2; fm++)
#pragma unroll
        for (int r = 0; r < 16; r++)
            gk[fm][r] = __shfl(gv4[fm], (r & 3) + 8 * (r >> 2) + 4 * lhi);

    float ks0 = 0.f, ks1 = 0.f;
#pragma unroll
    for (int fm = 0; fm < 2; fm++) {
#pragma unroll
        for (int fn = 0; fn < 2; fn++) {
            const int o = wn * 64 + fn * 32 + l31;   // <64: k-ch, >=64: v-ch
            const int sw = (o & 7) << 3;
#pragma unroll
            for (int rg = 0; rg < 4; rg++) {
                ushort4 pk4;
                unsigned short* pp = (unsigned short*)&pk4;
#pragma unroll
                for (int j = 0; j < 4; j++) {
                    const int r = rg * 4 + j;
                    float val = acc[fm][fn][r];
                    if (isK) {
                        float kvl = elu1(val) * gk[fm][r];
                        if (fn == 0) ks0 += kvl; else ks1 += kvl;
                        pp[j] = f2bf(kvl);
                    } else {
                        pp[j] = f2bf(val);
                    }
                }
                // regs rg*4..rg*4+3 are 4 contiguous pixels; swizzle flips
                // bits 3..5 only, so the 4-run stays contiguous.
                const int px0 = wm * 64 + fm * 32 + rg * 8 + 4 * lhi;
                *(ushort4*)&kvS[(size_t)o * 128 + (px0 ^ sw)] = pk4;
            }
        }
    }
    if (isK) {
        atomicAdd(&ksump[(size_t)(b * 8 + h) * 64 + l31], ks0);
        atomicAdd(&ksump[(size_t)(b * 8 + h) * 64 + 32 + l31], ks1);
    }
    __syncthreads();   // kvS fully written

    // kv partial: 64x64 over K=128 pixels; 4 waves, 32x32 quadrants
    f32x16 kva;
#pragma unroll
    for (int r = 0; r < 16; r++) kva[r] = 0.f;
#pragma unroll
    for (int pk = 0; pk < 8; pk++) {
        const int co = ((pk * 2 + lhi) ^ (l31 & 7)) * 8;
        bf16x8 kf = *(const bf16x8*)&kvS[(size_t)(wm * 32 + l31) * 128 + co];
        bf16x8 vf = *(const bf16x8*)&kvS[(size_t)(64 + wn * 32 + l31) * 128 + co];
        kva = __builtin_amdgcn_mfma_f32_32x32x16_bf16(kf, vf, kva, 0, 0, 0);
    }
    // private partial slot: plain coalesced stores, no atomics
    float* kvb = kvq + ((size_t)(b * 8 + h) * 32 + blockIdx.x) * 4096;
#pragma unroll
    for (int r = 0; r < 16; r++) {
        const int d = wm * 32 + (r & 3) + 8 * (r >> 2) + 4 * lhi;
        kvb[(size_t)d * 64 + wn * 32 + l31] = kva[r];
    }
}

// ---------------- K2: kv partial reduce (32 slots -> kvp) ----------------
// grid 256 (64 bh x 4 quarter), 256 threads; each thread one float4 chain.
__global__ __launch_bounds__(256) void k_kvred(
    const float* __restrict__ kvq, float* __restrict__ kvp)
{
    const int bh = blockIdx.x >> 2, q4 = blockIdx.x & 3;
    const float4* src = (const float4*)(kvq + (size_t)bh * 32 * 4096)
                      + q4 * 256 + threadIdx.x;
    float4 s; s.x = 0.f; s.y = 0.f; s.z = 0.f; s.w = 0.f;
#pragma unroll 8
    for (int i = 0; i < 32; i++) {
        float4 v = src[(size_t)i * 1024];
        s.x += v.x; s.y += v.y; s.z += v.z; s.w += v.w;
    }
    ((float4*)(kvp + (size_t)bh * 4096))[q4 * 256 + threadIdx.x] = s;
}

// ---------------- K3: out = z * kv^T q  (32x32x16, K=d=64) ----------------
#define LS3 72
__global__ __launch_bounds__(256) void k_out(
    const unsigned short* __restrict__ qT,   // B x 4096 x 512
    const float* __restrict__ kv, const float* __restrict__ ksum,
    unsigned short* __restrict__ outT)       // B x 4096 x 512
{
    const int bh = blockIdx.y, p0 = blockIdx.x * 128;
    const int b = bh >> 3, h = bh & 7;
    const int t = threadIdx.x, wave = t >> 6, lane = t & 63;
    const int l31 = lane & 31, lhi = lane >> 5;

    __shared__ unsigned short Aq[128 * LS3];  // [pixel][d]
    __shared__ unsigned short Bv[96 * LS3];   // [n][d]: 0..63 kvT, 64 hi, 65 lo, 66..95 zero

    const unsigned short* qg = qT + ((size_t)b * NPIX + p0) * HIDC + h * 64;
#pragma unroll
    for (int i = 0; i < 4; i++) {
        int idx = t + i * 256;
        int row = idx >> 3, c8 = (idx & 7) * 8;
        *(uint4*)&Aq[row * LS3 + c8] = *(const uint4*)&qg[(size_t)row * HIDC + c8];
    }
    const float* kvg = kv + (size_t)bh * 4096;
#pragma unroll
    for (int i = 0; i < 16; i++) {
        int idx = t + i * 256;
        int d = idx >> 6, e = idx & 63;
        Bv[e * LS3 + d] = f2bf(kvg[idx]);
    }
    if (t < 64) {
        float ksv = ksum[bh * 64 + t];
        unsigned short hi = f2bf(ksv);
        Bv[64 * LS3 + t] = hi;
        Bv[65 * LS3 + t] = f2bf(ksv - bf2f(hi));
    }
    for (int i = t; i < 30 * 64; i += 256)
        Bv[(66 + (i >> 6)) * LS3 + (i & 63)] = 0;
    __syncthreads();

    f32x16 acc[3];
#pragma unroll
    for (int j = 0; j < 3; j++)
#pragma unroll
        for (int r = 0; r < 16; r++) acc[j][r] = 0.f;

#pragma unroll
    for (int ksub = 0; ksub < 4; ksub++) {
        const int koff = ksub * 16 + lhi * 8;
        bf16x8 af = *(const bf16x8*)&Aq[(wave * 32 + l31) * LS3 + koff];
#pragma unroll
        for (int nf = 0; nf < 3; nf++) {
            bf16x8 bfg = *(const bf16x8*)&Bv[(nf * 32 + l31) * LS3 + koff];
            acc[nf] = __builtin_amdgcn_mfma_f32_32x32x16_bf16(af, bfg, acc[nf], 0, 0, 0);
        }
    }

    unsigned short* og = outT + ((size_t)b * NPIX + p0 + wave * 32) * HIDC + h * 64;
#pragma unroll
    for (int r = 0; r < 16; r++) {
        float hi = __shfl(acc[2][r], lane & 32);
        float lo = __shfl(acc[2][r], (lane & 32) | 1);
        float z = 1.f / (hi + lo + 1e-6f);
        int prow = (r & 3) + 8 * (r >> 2) + 4 * lhi;
#pragma unroll
        for (int nf = 0; nf < 2; nf++)
            og[(size_t)prow * HIDC + nf * 32 + l31] = f2bf(acc[nf][r] * z);
    }
}

// ---------------- K4: y = outT @ Wob^T + bout (16x16x32, async staging) ------
__global__ __launch_bounds__(256) void k_y(
    const unsigned short* __restrict__ outT,  // B x 4096 x 512
    const unsigned short* __restrict__ Wob,   // 256 x 512
    const float* __restrict__ bout,
    float* __restrict__ y)                    // B x 256 x 4096
{
    const int b  = blockIdx.z;
    const int m0 = blockIdx.x * 128;
    const int n0 = blockIdx.y * 128;
    const int t = threadIdx.x;
    const int wave = t >> 6, lane = t & 63;
    const int wm = wave >> 1, wn = wave & 1;
    const int lrow = lane & 15, quad = lane >> 4;

    __shared__ unsigned short As[128 * 64];
    __shared__ unsigned short Bs[128 * 64];

    const unsigned short* Ag = outT + ((size_t)b * NPIX + m0) * HIDC;
    const unsigned short* Bg = Wob + (size_t)n0 * HIDC;

    f32x4 acc[4][4];
#pragma unroll
    for (int i = 0; i < 4; i++)
#pragma unroll
        for (int j = 0; j < 4; j++) acc[i][j] = (f32x4){0.f, 0.f, 0.f, 0.f};

    const int r8  = lane >> 3;
    const int jg8 = (((lane & 7) ^ r8) & 7) * 8;
    const int xswA = (lrow & 7);

    for (int k0 = 0; k0 < HIDC; k0 += 64) {
#pragma unroll
        for (int i = 0; i < 4; i++) {
            const int rowg = wave * 32 + i * 8;
            gl16(&Ag[(size_t)(rowg + r8) * HIDC + k0 + jg8], &As[rowg * 64]);
            gl16(&Bg[(size_t)(rowg + r8) * HIDC + k0 + jg8], &Bs[rowg * 64]);
        }
        __syncthreads();
#pragma unroll
        for (int ksb = 0; ksb < 2; ksb++) {
            bf16x8 af[4], bfr[4];
#pragma unroll
            for (int mt = 0; mt < 4; mt++) {
                const int row = wm * 64 + mt * 16 + lrow;
                af[mt] = *(const bf16x8*)&As[row * 64 + (((ksb * 4 + quad) ^ xswA)) * 8];
            }
#pragma unroll
            for (int nt = 0; nt < 4; nt++) {
                const int row = wn * 64 + nt * 16 + lrow;
                bfr[nt] = *(const bf16x8*)&Bs[row * 64 + (((ksb * 4 + quad) ^ xswA)) * 8];
            }
#pragma unroll
            for (int mt = 0; mt < 4; mt++)
#pragma unroll
                for (int nt = 0; nt < 4; nt++)
                    acc[mt][nt] = __builtin_amdgcn_mfma_f32_16x16x32_bf16(
                        af[mt], bfr[nt], acc[mt][nt], 0, 0, 0);
        }
        __syncthreads();
    }

#pragma unroll
    for (int mt = 0; mt < 4; mt++) {
        const int pixel0 = m0 + wm * 64 + mt * 16 + quad * 4;
#pragma unroll
        for (int nt = 0; nt < 4; nt++) {
            const int o = n0 + wn * 64 + nt * 16 + lrow;
            const float bias = bout[o];
            f32x4 a = acc[mt][nt];
            float4 st; st.x = a[0] + bias; st.y = a[1] + bias;
            st.z = a[2] + bias; st.w = a[3] + bias;
            *(float4*)&y[((size_t)b * DIMC + o) * NPIX + pixel0] = st;
        }
    }
}

extern "C" void kernel_launch(void* const* d_in, const int* in_sizes, int n_in,
                              void* d_out, int out_size, void* d_ws, size_t ws_size,
                              hipStream_t stream) {
    (void)in_sizes; (void)n_in; (void)out_size; (void)ws_size;
    const float* x    = (const float*)d_in[0];
    const float* cm   = (const float*)d_in[1];
    const float* Wqkv = (const float*)d_in[2];
    const float* Wout = (const float*)d_in[3];
    const float* bout = (const float*)d_in[4];
    const float* csp  = (const float*)d_in[5];
    float* y = (float*)d_out;

    const size_t qn = (size_t)BATCH * HIDC * NPIX;
    char* ws = (char*)d_ws;
    unsigned short* qT   = (unsigned short*)ws;                 ws += qn * 2;
    unsigned short* outT = (unsigned short*)ws;                 ws += qn * 2;
    unsigned short* xT   = outT;  // alias OK: k_tx->k_fused reads xT before k_out writes outT
    float* kvp   = (float*)ws;                                  ws += (size_t)64 * 64 * 64 * 4;
    float* ksump = (float*)ws;                                  ws += (size_t)64 * 64 * 4;
    float* kvq   = (float*)ws;                                  ws += (size_t)64 * 32 * 4096 * 4;
    unsigned short* Wb  = (unsigned short*)ws;                  ws += (size_t)1536 * 256 * 2;
    unsigned short* Wob = (unsigned short*)ws;

    hipMemsetAsync(ksump, 0, (size_t)64 * 64 * sizeof(float), stream);
    k_convW<<<512, 256, 0, stream>>>(Wqkv, Wout, Wb, Wob);
    k_tx   <<<dim3(128, 8, 8), 256, 0, stream>>>(x, xT);
    k_fused<<<dim3(32, 12, 8), 256, 0, stream>>>(xT, Wb, cm, csp, qT, kvq, ksump);
    k_kvred<<<256, 256, 0, stream>>>(kvq, kvp);
    k_out  <<<dim3(32, 64),    256, 0, stream>>>(qT, kvp, ksump, outT);
    k_y    <<<dim3(32, 2, 8),  256, 0, stream>>>(outT, Wob, bout, y);
}

// Round 8
// 199.904 us; speedup vs baseline: 1.4063x; 1.0511x over previous
//
#include <hip/hip_runtime.h>
#include <stdint.h>

// LinearAttention MI355X round 12: fuse k_out + k_y -> k_oy. outT never hits
// HBM: per (64px, b) block, loop over 8 heads {out-GEMM (C lane=px, z-scale
// lane-local) -> 8KB swizzled LDS bounce -> y-GEMM accumulating in registers}.
// Wout prepacked to fragment order (R8 formula). k_fused/k_kvred/k_tx
// verbatim round 11. B=8, DIM=256, HEADS=8, DHEAD=64, HID=512, NPIX=4096.

#define NPIX 4096
#define HIDC 512
#define DIMC 256
#define BATCH 8

typedef __attribute__((ext_vector_type(8))) short bf16x8;
typedef __attribute__((ext_vector_type(4))) float f32x4;
typedef __attribute__((ext_vector_type(16))) float f32x16;

__device__ __forceinline__ float bf2f(unsigned short h) {
    unsigned int u = ((unsigned int)h) << 16; float f;
    __builtin_memcpy(&f, &u, 4); return f;
}
__device__ __forceinline__ unsigned short f2bf(float f) {
    unsigned int u; __builtin_memcpy(&u, &f, 4);
    u += 0x7fffu + ((u >> 16) & 1u);
    return (unsigned short)(u >> 16);
}
__device__ __forceinline__ float elu1(float x) {
    return x > 0.f ? x + 1.f : __expf(x);
}
// async global->LDS, 16B per lane. LDS dest = wave-uniform base + lane*16.
__device__ __forceinline__ void gl16(const unsigned short* g, unsigned short* l) {
    __builtin_amdgcn_global_load_lds(
        (__attribute__((address_space(1))) const void*)g,
        (__attribute__((address_space(3))) void*)l, 16, 0, 0);
}

// ---------------- K0a: weight conversion ----------------
// Wqkv -> Wb linear bf16 (k_fused staging unchanged).
// Wout (256x512) -> Wpo packed fragment order (R8 formula):
//   o,c: og=o>>5, l31=o&31, ks=c>>4, lhi=(c>>3)&1, j=c&7
//   Wpo[og*16384 + ks*512 + (l31*2+lhi)*8 + j]
__global__ __launch_bounds__(256) void k_convW(
    const float* __restrict__ Wqkv, const float* __restrict__ Wout,
    unsigned short* __restrict__ Wb, unsigned short* __restrict__ Wpo)
{
    int i4 = (blockIdx.x * 256 + threadIdx.x) * 4;
    const int NW1 = 1536 * 256;
    if (i4 < NW1) {
        float4 v = *(const float4*)&Wqkv[i4];
        ushort4 u; u.x = f2bf(v.x); u.y = f2bf(v.y); u.z = f2bf(v.z); u.w = f2bf(v.w);
        *(ushort4*)&Wb[i4] = u;
    } else {
        int jj = i4 - NW1;
        float4 v = *(const float4*)&Wout[jj];
        ushort4 u; u.x = f2bf(v.x); u.y = f2bf(v.y); u.z = f2bf(v.z); u.w = f2bf(v.w);
        const int o = jj >> 9, c = jj & 511;
        const int og = o >> 5, l31 = o & 31;
        const int ks = c >> 4, lhi = (c >> 3) & 1, j = c & 7;
        *(ushort4*)&Wpo[og * 16384 + ks * 512 + (l31 * 2 + lhi) * 8 + j] = u;
    }
}

// ---------------- K0b: x transpose+convert ----------------
__global__ __launch_bounds__(256) void k_tx(
    const float* __restrict__ x, unsigned short* __restrict__ xT)
{
    __shared__ float tile[32][33];
    const int n0 = blockIdx.x * 32, c0 = blockIdx.y * 32, b = blockIdx.z;
    const int t = threadIdx.x;
    const int r = t >> 3, c4 = (t & 7) * 4;
    float4 v = *(const float4*)&x[((size_t)b * DIMC + c0 + r) * NPIX + n0 + c4];
    tile[r][c4 + 0] = v.x; tile[r][c4 + 1] = v.y;
    tile[r][c4 + 2] = v.z; tile[r][c4 + 3] = v.w;
    __syncthreads();
    ushort4 o;
    unsigned short* op = (unsigned short*)&o;
#pragma unroll
    for (int i = 0; i < 4; i++) op[i] = f2bf(tile[c4 + i][r]);
    *(ushort4*)&xT[((size_t)b * NPIX + n0 + r) * DIMC + c0 + c4] = o;
}

// ---------------- K1: fused qkv GEMM + kv/ksum epilogue (round-11 verbatim) --
__global__ __launch_bounds__(256) void k_fused(
    const unsigned short* __restrict__ xT,   // B x 4096 x 256
    const unsigned short* __restrict__ Wb,   // 1536 x 256
    const float* __restrict__ cmp,           // B x 4096
    const float* __restrict__ csp,
    unsigned short* __restrict__ qT,         // B x 4096 x 512 (pixel-major)
    float* __restrict__ kvq,                 // (B*8) x 32 x 64 x 64 partials
    float* __restrict__ ksump)               // (B*8) x 64
{
    const int b  = blockIdx.z;
    const int m0 = blockIdx.x * 128;
    const int yb = blockIdx.y;               // 0..3 = q, 4..11 = head yb-4
    const int h  = yb - 4;
    const int t = threadIdx.x;
    const int wave = t >> 6, lane = t & 63;
    const int wm = wave >> 1, wn = wave & 1;
    const int l31 = lane & 31, lhi = lane >> 5;

    __shared__ unsigned short sh[128 * 128];        // 32 KB
    unsigned short* As  = sh;                       // [128 px][64 k]
    unsigned short* Bs  = sh + 128 * 64;            // [128 o ][64 k]
    unsigned short* kvS = sh;                       // epilogue reuse [128][128]

    const unsigned short* Ag = xT + ((size_t)b * NPIX + m0) * DIMC;

    f32x16 acc[2][2];
#pragma unroll
    for (int i = 0; i < 2; i++)
#pragma unroll
        for (int j = 0; j < 2; j++)
#pragma unroll
            for (int r = 0; r < 16; r++) acc[i][j][r] = 0.f;

    const int r8  = lane >> 3;
    const int jg8 = (((lane & 7) ^ r8) & 7) * 8;     // swizzled global chunk
    const int xsw = (l31 & 7);

    for (int k0 = 0; k0 < DIMC; k0 += 64) {
#pragma unroll
        for (int i = 0; i < 4; i++) {
            const int rowg = wave * 32 + i * 8;
            const int arow = rowg + r8;
            gl16(&Ag[(size_t)arow * DIMC + k0 + jg8], &As[rowg * 64]);
            int wrow;
            if (yb < 4) wrow = yb * 128 + arow;
            else wrow = (arow < 64) ? (512 + h * 64 + arow)
                                    : (1024 + h * 64 + (arow - 64));
            gl16(&Wb[(size_t)wrow * DIMC + k0 + jg8], &Bs[rowg * 64]);
        }
        __syncthreads();
#pragma unroll
        for (int ks = 0; ks < 4; ks++) {
            const int coff = ((ks * 2 + lhi) ^ xsw) * 8;
            bf16x8 af[2], bfg[2];
#pragma unroll
            for (int fm = 0; fm < 2; fm++)
                af[fm] = *(const bf16x8*)&As[(wm * 64 + fm * 32 + l31) * 64 + coff];
#pragma unroll
            for (int fn = 0; fn < 2; fn++)
                bfg[fn] = *(const bf16x8*)&Bs[(wn * 64 + fn * 32 + l31) * 64 + coff];
#pragma unroll
            for (int fm = 0; fm < 2; fm++)
#pragma unroll
                for (int fn = 0; fn < 2; fn++)
                    acc[fm][fn] = __builtin_amdgcn_mfma_f32_32x32x16_bf16(
                        af[fm], bfg[fn], acc[fm][fn], 0, 0, 0);
        }
        __syncthreads();
    }

    if (yb < 4) {
        const int n0 = yb * 128;
#pragma unroll
        for (int fm = 0; fm < 2; fm++) {
            const int pbase = m0 + wm * 64 + fm * 32;
#pragma unroll
            for (int fn = 0; fn < 2; fn++) {
                const int o = n0 + wn * 64 + fn * 32 + l31;
#pragma unroll
                for (int r = 0; r < 16; r++) {
                    int prow = pbase + (r & 3) + 8 * (r >> 2) + 4 * lhi;
                    qT[((size_t)b * NPIX + prow) * HIDC + o] = f2bf(elu1(acc[fm][fn][r]));
                }
            }
        }
        return;
    }

    const float cs = *csp;
    const bool isK = (wn == 0);
    float gv4[2];
#pragma unroll
    for (int fm = 0; fm < 2; fm++)
        gv4[fm] = 1.f + cs * cmp[(size_t)b * NPIX + m0 + wm * 64 + fm * 32 + l31];

    float gk[2][16];
#pragma unroll
    for (int fm = 0; fm < 2; fm++)
#pragma unroll
        for (int r = 0; r < 16; r++)
            gk[fm][r] = __shfl(gv4[fm], (r & 3) + 8 * (r >> 2) + 4 * lhi);

    float ks0 = 0.f, ks1 = 0.f;
#pragma unroll
    for (int fm = 0; fm < 2; fm++) {
#pragma unroll
        for (int fn = 0; fn < 2; fn++) {
            const int o = wn * 64 + fn * 32 + l31;   // <64: k-ch, >=64: v-ch
            const int sw = (o & 7) << 3;
#pragma unroll
            for (int rg = 0; rg < 4; rg++) {
                ushort4 pk4;
                unsigned short* pp = (unsigned short*)&pk4;
#pragma unroll
                for (int j = 0; j < 4; j++) {
                    const int r = rg * 4 + j;
                    float val = acc[fm][fn][r];
                    if (isK) {
                        float kvl = elu1(val) * gk[fm][r];
                        if (fn == 0) ks0 += kvl; else ks1 += kvl;
                        pp[j] = f2bf(kvl);
                    } else {
                        pp[j] = f2bf(val);
                    }
                }
                const int px0 = wm * 64 + fm * 32 + rg * 8 + 4 * lhi;
                *(ushort4*)&kvS[(size_t)o * 128 + (px0 ^ sw)] = pk4;
            }
        }
    }
    if (isK) {
        atomicAdd(&ksump[(size_t)(b * 8 + h) * 64 + l31], ks0);
        atomicAdd(&ksump[(size_t)(b * 8 + h) * 64 + 32 + l31], ks1);
    }
    __syncthreads();   // kvS fully written

    f32x16 kva;
#pragma unroll
    for (int r = 0; r < 16; r++) kva[r] = 0.f;
#pragma unroll
    for (int pk = 0; pk < 8; pk++) {
        const int co = ((pk * 2 + lhi) ^ (l31 & 7)) * 8;
        bf16x8 kf = *(const bf16x8*)&kvS[(size_t)(wm * 32 + l31) * 128 + co];
        bf16x8 vf = *(const bf16x8*)&kvS[(size_t)(64 + wn * 32 + l31) * 128 + co];
        kva = __builtin_amdgcn_mfma_f32_32x32x16_bf16(kf, vf, kva, 0, 0, 0);
    }
    float* kvb = kvq + ((size_t)(b * 8 + h) * 32 + blockIdx.x) * 4096;
#pragma unroll
    for (int r = 0; r < 16; r++) {
        const int d = wm * 32 + (r & 3) + 8 * (r >> 2) + 4 * lhi;
        kvb[(size_t)d * 64 + wn * 32 + l31] = kva[r];
    }
}

// ---------------- K2: kv partial reduce (32 slots -> kvp) ----------------
__global__ __launch_bounds__(256) void k_kvred(
    const float* __restrict__ kvq, float* __restrict__ kvp)
{
    const int bh = blockIdx.x >> 2, q4 = blockIdx.x & 3;
    const float4* src = (const float4*)(kvq + (size_t)bh * 32 * 4096)
                      + q4 * 256 + threadIdx.x;
    float4 s; s.x = 0.f; s.y = 0.f; s.z = 0.f; s.w = 0.f;
#pragma unroll 8
    for (int i = 0; i < 32; i++) {
        float4 v = src[(size_t)i * 1024];
        s.x += v.x; s.y += v.y; s.z += v.z; s.w += v.w;
    }
    ((float4*)(kvp + (size_t)bh * 4096))[q4 * 256 + threadIdx.x] = s;
}

// ---------------- K3: fused out+y: y = Wout·(z·kv^T q) + bout ----------------
// grid (64 px-tiles of 64, 8 b) = 512 blocks (2/CU), 256 thr = 4 waves.
// Per head h: out-GEMM: A = kvT (LDS, pad-72, rows=e), B = q (LDS, XOR-swz,
// rows=px) -> C lane=px, regs=e. z lane-local. Bounce out to outS[px][64]
// (kvS-style XOR swizzle), then y-GEMM: A = Wpo frags (L2), B = outS
// -> y acc in regs (lane=px, regs=o). Waves: pxh=wave&1; eh/oh=wave>>1.
__global__ __launch_bounds__(256, 2) void k_oy(
    const unsigned short* __restrict__ qT,   // B x 4096 x 512
    const float* __restrict__ kvp,           // (B*8) x 64 x 64  (d-major)
    const float* __restrict__ ksum,          // (B*8) x 64
    const unsigned short* __restrict__ Wpo,  // packed 256 x 512
    const float* __restrict__ bout,
    float* __restrict__ y)                   // B x 256 x 4096
{
    const int b  = blockIdx.y;
    const int px0 = blockIdx.x * 64;
    const int t = threadIdx.x;
    const int wave = t >> 6, lane = t & 63;
    const int pxh = wave & 1, whi = wave >> 1;   // whi: eh (out) / oh (y)
    const int l31 = lane & 31, lhi = lane >> 5;
    const int lidx = (l31 * 2 + lhi) * 8;

    __shared__ unsigned short qS[2][64 * 64];   // 16 KB q dbuf (XOR-swz)
    __shared__ unsigned short kvS2[64 * 72];    // 9 KB kvT [e][d] pad-72
    __shared__ unsigned short outS[64 * 64];    // 8 KB out [px][e] XOR-swz
    __shared__ float ksS[64];

    const int r8 = lane >> 3;
    const int jg8 = ((lane & 7) ^ r8) * 8;

    // q stage: head h -> buf. Each wave 16 rows = 2 gl16 calls of 8 rows.
    auto stageQ = [&](int h, int buf) {
        const unsigned short* qg = qT + ((size_t)b * NPIX + px0) * HIDC + h * 64;
#pragma unroll
        for (int i = 0; i < 2; i++) {
            const int rowb = wave * 16 + i * 8;
            gl16(&qg[(size_t)(rowb + r8) * HIDC + jg8], &qS[buf][rowb * 64]);
        }
    };
    // kvT + ksum stage for head h (scalar; 16 elems/thread)
    auto stageKV = [&](int h) {
        const float* kvg = kvp + (size_t)(b * 8 + h) * 4096;
#pragma unroll
        for (int i = 0; i < 16; i++) {
            int idx = t + i * 256;
            int d = idx >> 6, e = idx & 63;
            kvS2[e * 72 + d] = f2bf(kvg[idx]);
        }
        if (t < 64) ksS[t] = ksum[(size_t)(b * 8 + h) * 64 + t];
    };

    stageQ(0, 0);
    stageKV(0);

    f32x16 yacc[4];
#pragma unroll
    for (int mt = 0; mt < 4; mt++)
#pragma unroll
        for (int r = 0; r < 16; r++) yacc[mt][r] = 0.f;

    int cur = 0;
    __syncthreads();

#pragma unroll 1
    for (int h = 0; h < 8; h++) {
        // ---- out-GEMM: C[e][px], lane = px ----
        bf16x8 qf[4];
#pragma unroll
        for (int s = 0; s < 4; s++)
            qf[s] = *(const bf16x8*)&qS[cur][(pxh * 32 + l31) * 64
                                            + (((s * 2 + lhi) ^ (l31 & 7)) * 8)];
        f32x16 oacc;
#pragma unroll
        for (int r = 0; r < 16; r++) oacc[r] = 0.f;
#pragma unroll
        for (int s = 0; s < 4; s++) {
            bf16x8 kvf = *(const bf16x8*)&kvS2[(whi * 32 + l31) * 72 + s * 16 + lhi * 8];
            oacc = __builtin_amdgcn_mfma_f32_32x32x16_bf16(kvf, qf[s], oacc, 0, 0, 0);
        }
        // ---- z: lane-local VALU dot q·ksum over this lane's 32 d's ----
        float den = 0.f;
#pragma unroll
        for (int s = 0; s < 4; s++) {
            f32x4 ka = *(const f32x4*)&ksS[s * 16 + lhi * 8];
            f32x4 kb = *(const f32x4*)&ksS[s * 16 + lhi * 8 + 4];
            const unsigned short* qp = (const unsigned short*)&qf[s];
#pragma unroll
            for (int j = 0; j < 4; j++) {
                den += bf2f(qp[j]) * ka[j];
                den += bf2f(qp[4 + j]) * kb[j];
            }
        }
        den += __shfl_xor(den, 32);
        const float z = 1.f / (den + 1e-6f);

        // pack z-scaled out into ushort4 groups (regs 4rg..4rg+3 -> e run of 4)
        ushort4 op4[4];
#pragma unroll
        for (int rg = 0; rg < 4; rg++) {
            unsigned short* pp = (unsigned short*)&op4[rg];
#pragma unroll
            for (int j = 0; j < 4; j++)
                pp[j] = f2bf(oacc[rg * 4 + j] * z);
        }

        __syncthreads();   // A: all waves done reading outS (prev) & kvS2/ksS
        {
            const int px = pxh * 32 + l31;
#pragma unroll
            for (int rg = 0; rg < 4; rg++)
                *(ushort4*)&outS[px * 64 + (((whi * 4 + rg) ^ (px & 7)) * 8) + 4 * lhi]
                    = op4[rg];
        }
        if (h < 7) { stageQ(h + 1, cur ^ 1); stageKV(h + 1); }
        __syncthreads();   // B: outS + next kv staged

        // ---- y-GEMM: A = Wpo frags, B = outS; acc lane = px, regs = o ----
#pragma unroll
        for (int k16 = 0; k16 < 4; k16++) {
            const int px = pxh * 32 + l31;
            bf16x8 of = *(const bf16x8*)&outS[px * 64 + (((k16 * 2 + lhi) ^ (px & 7)) * 8)];
#pragma unroll
            for (int mt = 0; mt < 4; mt++) {
                bf16x8 wf = *(const bf16x8*)&Wpo[(size_t)(whi * 4 + mt) * 16384
                                                 + (h * 4 + k16) * 512 + lidx];
                yacc[mt] = __builtin_amdgcn_mfma_f32_32x32x16_bf16(wf, of, yacc[mt], 0, 0, 0);
            }
        }
        cur ^= 1;
    }

    // ---- epilogue: y stores (coalesced 128B runs) + bias ----
#pragma unroll
    for (int mt = 0; mt < 4; mt++) {
#pragma unroll
        for (int r = 0; r < 16; r++) {
            const int o = whi * 128 + mt * 32 + (r & 3) + 8 * (r >> 2) + 4 * lhi;
            y[((size_t)b * DIMC + o) * NPIX + px0 + pxh * 32 + l31]
                = yacc[mt][r] + bout[o];
        }
    }
}

extern "C" void kernel_launch(void* const* d_in, const int* in_sizes, int n_in,
                              void* d_out, int out_size, void* d_ws, size_t ws_size,
                              hipStream_t stream) {
    (void)in_sizes; (void)n_in; (void)out_size; (void)ws_size;
    const float* x    = (const float*)d_in[0];
    const float* cm   = (const float*)d_in[1];
    const float* Wqkv = (const float*)d_in[2];
    const float* Wout = (const float*)d_in[3];
    const float* bout = (const float*)d_in[4];
    const float* csp  = (const float*)d_in[5];
    float* y = (float*)d_out;

    const size_t qn = (size_t)BATCH * HIDC * NPIX;
    char* ws = (char*)d_ws;
    unsigned short* qT   = (unsigned short*)ws;                 ws += qn * 2;
    unsigned short* xT   = (unsigned short*)ws;                 ws += qn * 2;
    float* kvp   = (float*)ws;                                  ws += (size_t)64 * 64 * 64 * 4;
    float* ksump = (float*)ws;                                  ws += (size_t)64 * 64 * 4;
    float* kvq   = (float*)ws;                                  ws += (size_t)64 * 32 * 4096 * 4;
    unsigned short* Wb  = (unsigned short*)ws;                  ws += (size_t)1536 * 256 * 2;
    unsigned short* Wpo = (unsigned short*)ws;

    hipMemsetAsync(ksump, 0, (size_t)64 * 64 * sizeof(float), stream);
    k_convW<<<512, 256, 0, stream>>>(Wqkv, Wout, Wb, Wpo);
    k_tx   <<<dim3(128, 8, 8), 256, 0, stream>>>(x, xT);
    k_fused<<<dim3(32, 12, 8), 256, 0, stream>>>(xT, Wb, cm, csp, qT, kvq, ksump);
    k_kvred<<<256, 256, 0, stream>>>(kvq, kvp);
    k_oy   <<<dim3(64, 8),     256, 0, stream>>>(qT, kvp, ksump, Wpo, bout, y);
}